// Round 12
// baseline (6315.290 us; speedup 1.0000x reference)
//
#include <hip/hip_runtime.h>
#include <math.h>
#include <stdint.h>

// ---------------- problem constants ----------------
#define NB   64
#define TE   256
#define TD   200
#define MR   160

typedef _Float16 h2 __attribute__((ext_vector_type(2)));

__device__ __forceinline__ float dot2f(h2 a, h2 b, float c){
  return __builtin_amdgcn_fdot2(a, b, c, false);
}
__device__ __forceinline__ h2 u2h(unsigned int u){ return __builtin_bit_cast(h2, u); }
__device__ __forceinline__ unsigned int h2u(h2 h){ return __builtin_bit_cast(unsigned int, h); }
__device__ __forceinline__ unsigned f2u(float f){ return __builtin_bit_cast(unsigned, f); }
__device__ __forceinline__ float u2f(unsigned u){ return __builtin_bit_cast(float, u); }

__device__ __forceinline__ float sigmf(float x){
  return __fdividef(1.f, 1.f + __expf(-x));
}
__device__ __forceinline__ float tanhf_(float x){
  float ax = fabsf(x);
  float e  = __expf(-2.f*ax);
  float r  = __fdividef(1.f - e, 1.f + e);
  return copysignf(r, x);
}

// ---------------- workspace layout (bytes) ----------------
static constexpr size_t OFF_PM   = 0;                       // f16 [B][t'][256 d]
static constexpr size_t OFF_ENCH = 8388608;                 // f16 [B][t'][256 d]
static constexpr size_t OFF_GIP  = 16777216;                // f16 [B][TD][768]; gip[t] reused post-consume:
                                                            //   words[0,128)=hA(t) ; [256,384)=d(t)
static constexpr size_t OFF_P    = 36438016;                // f16 [B][TD][512]
static constexpr size_t OFF_W2   = 49545216;                // h2 pool (small mats)
static constexpr size_t OFF_W8   = 50184192;                // uint4 pool (k_dec mats)
static constexpr size_t WS_NEEDED = 52936704;

// pool A (h2 slots): [kp][O] layouts for aux kernels
static constexpr size_t A_PW1  = 0;        // [80 kp][256]
static constexpr size_t A_PW2  = 20480;    // [128 kp][128]
static constexpr size_t A_WIHP = 36864;    // [64 kp][768]
static constexpr size_t A_MEMW = 86016;    // [128 kp][256]
static constexpr size_t A_MELW = 118784;   // [256 kp][160]

// pool B (uint4 slots): [kq][O] with 8 f16 per slot
static constexpr size_t B_ATTC = 0;        // [32 kq][768]
static constexpr size_t B_ATTH = 24576;
static constexpr size_t B_G1I  = 49152;
static constexpr size_t B_G1H  = 73728;
static constexpr size_t B_G2I  = 98304;
static constexpr size_t B_G2H  = 122880;
static constexpr size_t B_PROJ = 147456;   // [64 kq][256]
static constexpr size_t B_QW   = 163840;   // [32 kq][256]

// ---------------- K1a: f32 (O,K) row-major -> f16 [kp][O] (pool A) ----------------
__global__ void k_conv(const float* __restrict__ src, char* __restrict__ ws,
                       unsigned off_h2, int O, int Kh, int k0, int ld){
  int i = blockIdx.x*256 + threadIdx.x;
  if (i >= O*Kh) return;
  int o = i % O, kp = i / O;
  _Float16* dst = (_Float16*)(ws + OFF_W2) + 2*((size_t)off_h2 + i);
  dst[0] = (_Float16)src[(size_t)o*ld + k0 + 2*kp    ];
  dst[1] = (_Float16)src[(size_t)o*ld + k0 + 2*kp + 1];
}

// ---------------- K1b: f32 (O,K) row-major -> f16 [kq][O] packed x8 (pool B) ----------------
__global__ void k_conv8(const float* __restrict__ src, char* __restrict__ ws,
                        unsigned off16, int O, int Kq, int k0, int ld){
  int i = blockIdx.x*256 + threadIdx.x;
  if (i >= O*Kq) return;
  int o = i % O, kq = i / O;
  const float* s = src + (size_t)o*ld + k0 + kq*8;
  h2 p0, p1, p2, p3;
  p0.x=(_Float16)s[0]; p0.y=(_Float16)s[1];
  p1.x=(_Float16)s[2]; p1.y=(_Float16)s[3];
  p2.x=(_Float16)s[4]; p2.y=(_Float16)s[5];
  p3.x=(_Float16)s[6]; p3.y=(_Float16)s[7];
  uint4 r; r.x=h2u(p0); r.y=h2u(p1); r.z=h2u(p2); r.w=h2u(p3);
  ((uint4*)(ws + OFF_W8))[(size_t)off16 + i] = r;
}

// ---------------- K2: processed_memory (pm [b][t'][d]) + enc f16 copy ----------------
__global__ void k_pm(const float* __restrict__ enc, char* __restrict__ ws){
  int bt = blockIdx.x;             // b*256 + t
  int j  = threadIdx.x;
  const h2* mw = (const h2*)(ws + OFF_W2) + A_MEMW;
  _Float16* pmN  = (_Float16*)(ws + OFF_PM);
  _Float16* encH = (_Float16*)(ws + OFF_ENCH);
  __shared__ _Float16 e[256];
  float ev = enc[(size_t)bt*256 + j];
  e[j] = (_Float16)ev;
  encH[(size_t)bt*256 + j] = (_Float16)ev;
  __syncthreads();
  const h2* e2 = (const h2*)e;
  float acc = 0.f;
  #pragma unroll 8
  for (int kp=0; kp<128; ++kp) acc = dot2f(mw[kp*256 + j], e2[kp], acc);
  pmN[(size_t)bt*256 + j] = (_Float16)acc;     // [b][t'][d] layout
}

// ---------------- K3: prenet + gi_pre (all timesteps, parallel) ----------------
__global__ void k_pre(const float* __restrict__ xin, const float* __restrict__ b1,
                      const float* __restrict__ b2, const float* __restrict__ bih,
                      char* __restrict__ ws){
  int bt = blockIdx.x;             // b*TD + t
  int b = bt / TD, t = bt % TD;
  int j = threadIdx.x;
  const h2* w1 = (const h2*)(ws + OFF_W2) + A_PW1;
  const h2* w2 = (const h2*)(ws + OFF_W2) + A_PW2;
  const h2* wp = (const h2*)(ws + OFF_W2) + A_WIHP;
  _Float16* gip = (_Float16*)(ws + OFF_GIP) + (size_t)bt*768;
  __shared__ _Float16 xh[160];
  __shared__ _Float16 a1[256];
  __shared__ _Float16 pr[128];
  if (j < 160)
    xh[j] = (t==0) ? (_Float16)0.f : (_Float16)xin[((size_t)b*TD + (t-1))*MR + j];
  __syncthreads();
  {
    const h2* x2 = (const h2*)xh;
    float acc = b1[j];
    #pragma unroll 8
    for (int kp=0; kp<80; ++kp) acc = dot2f(w1[kp*256 + j], x2[kp], acc);
    a1[j] = (_Float16)fmaxf(acc, 0.f);
  }
  __syncthreads();
  if (j < 128){
    const h2* x2 = (const h2*)a1;
    float acc = b2[j];
    #pragma unroll 8
    for (int kp=0; kp<128; ++kp) acc = dot2f(w2[kp*128 + j], x2[kp], acc);
    pr[j] = (_Float16)fmaxf(acc, 0.f);
  }
  __syncthreads();
  {
    const h2* p2 = (const h2*)pr;
    for (int o=j; o<768; o+=256){
      float acc = bih[o];
      #pragma unroll 8
      for (int kp=0; kp<64; ++kp) acc = dot2f(wp[kp*768 + o], p2[kp], acc);
      gip[o] = (_Float16)acc;
    }
  }
}

// ---------------- K3b: zero per-batch progress flags (stop region of out) ----------------
__global__ void k_zero(float* __restrict__ out){
  int* prog = (int*)(out + (size_t)NB*TD*MR + (size_t)NB*TD*TE);
  if (threadIdx.x < 256) prog[threadIdx.x] = 0;
}

// ---------------- k_dec helpers ----------------
__device__ __forceinline__ float d4dot(uint4 w, uint4 x, float a){
  a = dot2f(u2h(w.x), u2h(x.x), a);
  a = dot2f(u2h(w.y), u2h(x.y), a);
  a = dot2f(u2h(w.z), u2h(x.z), a);
  a = dot2f(u2h(w.w), u2h(x.w), a);
  return a;
}

// dual-operand 4-stream GRU GEMV partials (full K both operands):
// r,z merge I+H partials; n keeps nI,nH separate (n = tanh(nI + r*nH)).
__device__ __forceinline__ void gemv4(const uint4* __restrict__ wI, const uint4* __restrict__ wH,
                                      const uint4* xI, const uint4* xH,
                                      int j, int ks, float* scr, int tid){
  float a0=0.f,a1=0.f,a2=0.f,a3=0.f;
  #pragma unroll 2
  for (int kq=ks*8; kq<ks*8+8; ++kq){
    uint4 xi = xI[kq];
    uint4 xh = xH[kq];
    a0 = d4dot(wI[kq*768 +       j], xi, a0);   // r (I)
    a1 = d4dot(wI[kq*768 + 256 + j], xi, a1);   // z (I)
    a2 = d4dot(wI[kq*768 + 512 + j], xi, a2);   // n (I)
    a0 = d4dot(wH[kq*768 +       j], xh, a0);   // r (+H)
    a1 = d4dot(wH[kq*768 + 256 + j], xh, a1);   // z (+H)
    a3 = d4dot(wH[kq*768 + 512 + j], xh, a3);   // n (H)
  }
  float* r = scr + tid*4;
  r[0]=a0; r[1]=a1; r[2]=a2; r[3]=a3;
}

// ---------------- K4: serial decoder, 4-stage per-batch pipeline ----------------
// grid = 256 blocks x 1024 threads. LDS ~153KB forces exactly ONE block per CU.
// x = (b&7) + 8*(role + 4*(b>>3))  -> batch's 4 roles share an XCD.
// QUAD layout for recurrent GEMVs: jj=tid>>2, kk=tid&3 — the 4 split-K partials
// of output jj sit in adjacent lanes of one wave; 2x shfl_down reduces them and
// the lane leader (kk==0) applies the nonlinearity in-register. No scr, fewer
// barriers in the serial chain.
// role 0 (A): wAH gemv+nonlin (hA in leader regs) -> q -> score (pm in LDS) ->
//             publish UNNORMALIZED e + flag; sum/outA tail overlaps P.
// role 1 (P): on e(t): sum in-wave; ctx from LDS enc (normalize by 1/sum) ->
//             FULL wAC partials (leaders store uSlot) -> flag -> proj -> d.
// role 2 (B1): GRU1 + residual.  role 3 (B2): GRU2 + residual -> pst.
// Handoffs: gip[t] words[0,128)=hA (A); [256,384)=d (P).
//   out1(t) -> out mel scratch [0, NB*TD*128) words (B1).
//   uSlot (wAC partials r/z/nI, 768 f32/batch) at word NB*TD*128 + b*768.
//   aSlot (e unnormalized, 256 f32/batch)     at word NB*TD*128 + NB*768 + b*256.
// Single slots race-free (flag-ordered as in prior rounds).
// Flags (out stop-region, k_post overwrites): pP=prog+0, pAl=+64, pD=+128, pB1=+192.
__global__ __launch_bounds__(1024) void k_dec(
    const int*   __restrict__ memlen,
    const float* __restrict__ att_bhh,
    const float* __restrict__ vw,
    const float* __restrict__ proj_b,
    const float* __restrict__ g1_bih, const float* __restrict__ g1_bhh,
    const float* __restrict__ g2_bih, const float* __restrict__ g2_bhh,
    float* __restrict__ out, char* __restrict__ ws)
{
  const int tid  = threadIdx.x;
  const int x    = blockIdx.x;
  const int y    = x >> 3;
  const int role = y & 3;
  const int b    = ((y >> 2) << 3) | (x & 7);
  const int ks   = tid >> 8;       // split-K quarter (block layout)
  const int j    = tid & 255;      // output index (block layout)
  const int jj   = tid >> 2;       // output index (quad layout)
  const int kk   = tid & 3;        // split-K quarter (quad layout)

  const uint4* W8 = (const uint4*)(ws + OFF_W8);
  int* prog = (int*)(out + (size_t)NB*TD*MR + (size_t)NB*TD*TE);
  int* pP   = prog;        // P->A: partials for A's step t ready (value t)
  int* pAl  = prog + 64;   // A->P: e(t)+hA(t) ready (value t+1)
  int* pD   = prog + 128;  // d(t) ready
  int* pB1  = prog + 192;  // out1(t) ready
  unsigned* gX = (unsigned*)((_Float16*)(ws + OFF_GIP) + (size_t)b*TD*768);
  unsigned* uSlot = (unsigned*)out + (size_t)NB*TD*128 + (size_t)b*768;            // wAC partials
  unsigned* aSlot = (unsigned*)out + (size_t)NB*TD*128 + (size_t)NB*768 + (size_t)b*256; // e

  __shared__ __align__(16) _Float16 hAh[256], ctxh[256], hh[256], dh[256];  // 2KB
  __shared__ float hf[256], df[256];                                        // 2KB
  __shared__ float qf[256], sc[256], al[256], vl[256];                      // 4KB
  __shared__ float scr[4096];                                               // 16KB
  __shared__ float red2[4];
  __shared__ __align__(16) uint4 pmL[8192];                                 // 128KB: pm (A) / enc (P)

  if (role == 0){
    //================= A: attention recurrence =================
    const uint4* wAH = W8 + B_ATTH;
    const uint4* wQ4 = W8 + B_QW;
    const uint4* pm4 = (const uint4*)(ws + OFF_PM) + (size_t)b*8192;     // [t'][d] uint4
    const _Float16* gipB = (const _Float16*)(ws + OFF_GIP) + (size_t)b*TD*768;
    float* outA = out + (size_t)NB*TD*MR + (size_t)b*TD*TE;
    const int ml = memlen[b];

    // pm -> LDS, XOR-swizzled (granule ^ (row&7)) to break 512B-stride conflicts
    for (int idx = tid; idx < 8192; idx += 1024){
      int tp = idx >> 5, g = idx & 31;
      pmL[(tp<<5) | (g ^ (tp & 7))] = pm4[idx];
    }
    if (tid < 256){ hAh[tid]=(_Float16)0.f; vl[tid]=vw[tid]; }
    __syncthreads();
    const uint4* hA4 = (const uint4*)hAh;
    float hAprev = 0.f;    // hA carried in lane-leader registers

    #pragma unroll 1
    for (int t=0; t<TD; ++t){
      //---- phase1: wAH gemv (quad layout) + in-wave reduce + leader nonlin ----
      float a0=0.f, a1=0.f, a3=0.f;
      #pragma unroll 2
      for (int i=0;i<8;++i){
        int kq = kk*8+i;
        uint4 xv = hA4[kq];
        a0 = d4dot(wAH[kq*768 +       jj], xv, a0);   // r (H)
        a1 = d4dot(wAH[kq*768 + 256 + jj], xv, a1);   // z (H)
        a3 = d4dot(wAH[kq*768 + 512 + jj], xv, a3);   // nH
      }
      a0 += __shfl_down(a0,2); a0 += __shfl_down(a0,1);
      a1 += __shfl_down(a1,2); a1 += __shfl_down(a1,1);
      a3 += __shfl_down(a3,2); a3 += __shfl_down(a3,1);
      if (t > 0 && tid==0){
        while (__hip_atomic_load(pP+b, __ATOMIC_RELAXED, __HIP_MEMORY_SCOPE_AGENT) < t)
          __builtin_amdgcn_s_sleep(1);
      }
      __syncthreads();
      if (kk==0){
        const _Float16* gp = gipB + (size_t)t*768;
        float s0=a0, s1=a1, s3=a3, s2=0.f;
        if (t > 0){
          s0 += u2f(__hip_atomic_load(uSlot +       jj, __ATOMIC_RELAXED, __HIP_MEMORY_SCOPE_AGENT));
          s1 += u2f(__hip_atomic_load(uSlot + 256 + jj, __ATOMIC_RELAXED, __HIP_MEMORY_SCOPE_AGENT));
          s2  = u2f(__hip_atomic_load(uSlot + 512 + jj, __ATOMIC_RELAXED, __HIP_MEMORY_SCOPE_AGENT));
        }
        float r = sigmf(s0 + (float)gp[jj]     + att_bhh[jj]);
        float z = sigmf(s1 + (float)gp[256+jj] + att_bhh[256+jj]);
        float n = tanhf_(s2 + (float)gp[512+jj] + r*(s3 + att_bhh[512+jj]));
        float h = (1.f-z)*n + z*hAprev;
        hAprev = h;
        hAh[jj] = (_Float16)h;
      }
      __syncthreads();
      //---- phase2: q gemv (quad layout) + publish hA(t) ----
      { float a=0.f;
        #pragma unroll 2
        for (int kq=kk*8; kq<kk*8+8; ++kq)
          a = d4dot(wQ4[kq*256 + jj], hA4[kq], a);
        a += __shfl_down(a,2); a += __shfl_down(a,1);
        if (kk==0) qf[jj] = a; }
      if (tid<128)
        __hip_atomic_store(gX + (size_t)t*384 + tid, ((const unsigned*)hAh)[tid],
                           __ATOMIC_RELAXED, __HIP_MEMORY_SCOPE_AGENT);
      __syncthreads();
      //---- phase3: score (pm from LDS, quad layout) -> e, publish e ----
      { float s=0.f;
        #pragma unroll
        for (int i=0;i<8;++i){
          int g = kk*8 + i;
          uint4 q4 = pmL[(jj<<5) | (g ^ (jj&7))];
          int d0 = kk*64 + i*8;
          h2 p0=u2h(q4.x), p1=u2h(q4.y), p2=u2h(q4.z), p3=u2h(q4.w);
          s += vl[d0+0]*tanhf_((float)p0.x + qf[d0+0]);
          s += vl[d0+1]*tanhf_((float)p0.y + qf[d0+1]);
          s += vl[d0+2]*tanhf_((float)p1.x + qf[d0+2]);
          s += vl[d0+3]*tanhf_((float)p1.y + qf[d0+3]);
          s += vl[d0+4]*tanhf_((float)p2.x + qf[d0+4]);
          s += vl[d0+5]*tanhf_((float)p2.y + qf[d0+5]);
          s += vl[d0+6]*tanhf_((float)p3.x + qf[d0+6]);
          s += vl[d0+7]*tanhf_((float)p3.y + qf[d0+7]);
        }
        s += __shfl_down(s,2); s += __shfl_down(s,1);
        if (kk==0){
          float e = (jj < ml) ? __expf(s) : 0.f;   // |score|<=sum|v|~10: safe
          sc[jj] = e;
          __hip_atomic_store(aSlot + jj, f2u(e),
                             __ATOMIC_RELAXED, __HIP_MEMORY_SCOPE_AGENT);
        } }
      __syncthreads();
      if (tid==0)
        __hip_atomic_store(pAl+b, t+1, __ATOMIC_RELEASE, __HIP_MEMORY_SCOPE_AGENT);
      //---- tail (overlaps P): normalize for attn-score output ----
      if (tid<256){
        float sv = sc[tid];
        #pragma unroll
        for (int o=32;o>0;o>>=1) sv += __shfl_down(sv,o,64);
        if ((tid&63)==0) red2[tid>>6]=sv;
      }
      __syncthreads();
      if (tid<256){
        float sum = red2[0]+red2[1]+red2[2]+red2[3];
        outA[(size_t)t*TE + tid] = sc[tid]*__fdividef(1.f,sum);
      }
    }
  } else if (role == 1){
    //================= P: sum + ctx + full wAC partials + proj =================
    const uint4* wAC  = W8 + B_ATTC;
    const uint4* wPRJ = W8 + B_PROJ;
    const unsigned* encW = (const unsigned*)(ws + OFF_ENCH) + (size_t)b*TE*128;
    _Float16* pstB = (_Float16*)(ws + OFF_P) + (size_t)b*TD*512;
    unsigned* encL = (unsigned*)pmL;                 // 128KB enc in LDS
    const uint4* hA4  = (const uint4*)hAh;
    const uint4* ctx4 = (const uint4*)ctxh;
    const int tsl = tid>>7, dp = tid&127;

    // enc -> LDS (once)
    for (int idx = tid; idx < 32768; idx += 1024) encL[idx] = encW[idx];
    __syncthreads();

    #pragma unroll 1
    for (int t=0; t<TD; ++t){
      //---- wait e(t); read e (+in-wave sum) and hA(t) ----
      if (tid==0){
        while (__hip_atomic_load(pAl+b, __ATOMIC_RELAXED, __HIP_MEMORY_SCOPE_AGENT) < t+1)
          __builtin_amdgcn_s_sleep(1);
      }
      __syncthreads();
      if (tid<256){
        float e = u2f(__hip_atomic_load(aSlot + tid, __ATOMIC_RELAXED, __HIP_MEMORY_SCOPE_AGENT));
        al[tid] = e;
        float sv = e;
        #pragma unroll
        for (int o=32;o>0;o>>=1) sv += __shfl_down(sv,o,64);
        if ((tid&63)==0) red2[tid>>6]=sv;
      }
      if (tid >= 256 && tid < 384)
        ((unsigned*)hAh)[tid-256] = __hip_atomic_load(gX + (size_t)t*384 + (tid-256),
                                                      __ATOMIC_RELAXED, __HIP_MEMORY_SCOPE_AGENT);
      __syncthreads();
      //---- ctx[d] = (sum_t' e[t']*enc[t'][d]) / sum (enc in LDS) ----
      { float c0=0.f, c1=0.f;
        #pragma unroll 8
        for (int tp=tsl*32; tp<tsl*32+32; ++tp){
          float a = al[tp];
          h2 e = u2h(encL[tp*128 + dp]);
          c0 += a*(float)e.x; c1 += a*(float)e.y;
        }
        scr[tid*2]=c0; scr[tid*2+1]=c1; }
      __syncthreads();
      if (tid<128){
        float c0=0.f, c1=0.f;
        #pragma unroll
        for (int k=0;k<8;++k){ c0 += scr[(k*128+tid)*2]; c1 += scr[(k*128+tid)*2+1]; }
        float rs = __fdividef(1.f, red2[0]+red2[1]+red2[2]+red2[3]);
        h2 c; c.x=(_Float16)(c0*rs); c.y=(_Float16)(c1*rs);
        unsigned w = h2u(c);
        ((unsigned*)ctxh)[tid] = w;
        ((unsigned*)pstB)[(size_t)t*256 + 128 + tid] = w;   // p ctx half
      }
      __syncthreads();
      //---- FULL wAC partials (quad layout, leaders store uSlot) ----
      { float a0=0.f, a1=0.f, a2=0.f;
        #pragma unroll 2
        for (int kq=kk*8; kq<kk*8+8; ++kq){
          uint4 xv = ctx4[kq];
          a0 = d4dot(wAC[kq*768 +       jj], xv, a0);
          a1 = d4dot(wAC[kq*768 + 256 + jj], xv, a1);
          a2 = d4dot(wAC[kq*768 + 512 + jj], xv, a2);
        }
        a0 += __shfl_down(a0,2); a0 += __shfl_down(a0,1);
        a1 += __shfl_down(a1,2); a1 += __shfl_down(a1,1);
        a2 += __shfl_down(a2,2); a2 += __shfl_down(a2,1);
        if (kk==0){
          __hip_atomic_store(uSlot +       jj, f2u(a0), __ATOMIC_RELAXED, __HIP_MEMORY_SCOPE_AGENT);
          __hip_atomic_store(uSlot + 256 + jj, f2u(a1), __ATOMIC_RELAXED, __HIP_MEMORY_SCOPE_AGENT);
          __hip_atomic_store(uSlot + 512 + jj, f2u(a2), __ATOMIC_RELAXED, __HIP_MEMORY_SCOPE_AGENT);
        } }
      __syncthreads();
      if (tid==0)
        __hip_atomic_store(pP+b, t+1, __ATOMIC_RELEASE, __HIP_MEMORY_SCOPE_AGENT);
      //---- d = [hA, ctx] @ proj_w.T + proj_b (262KB) ----
      { float a=0.f;
        #pragma unroll 2
        for (int kq=ks*16; kq<ks*16+16; ++kq){
          uint4 xa = (kq < 32) ? hA4[kq] : ctx4[kq-32];
          a = d4dot(wPRJ[kq*256 + j], xa, a);
        }
        scr[tid]=a; }
      __syncthreads();
      if (tid<128){
        const int o0 = 2*tid, o1 = o0+1;
        float d0 = scr[o0]+scr[256+o0]+scr[512+o0]+scr[768+o0] + proj_b[o0];
        float d1 = scr[o1]+scr[256+o1]+scr[512+o1]+scr[768+o1] + proj_b[o1];
        h2 p; p.x=(_Float16)d0; p.y=(_Float16)d1;
        __hip_atomic_store(gX + (size_t)t*384 + 256 + tid, h2u(p),
                           __ATOMIC_RELAXED, __HIP_MEMORY_SCOPE_AGENT);
      }
      __syncthreads();
      if (tid==0)
        __hip_atomic_store(pD+b, t+1, __ATOMIC_RELEASE, __HIP_MEMORY_SCOPE_AGENT);
    }
  } else {
    //================= B1 / B2: decoder GRUs =================
    const bool isB1 = (role == 2);
    const uint4* wI = W8 + (isB1 ? B_G1I : B_G2I);
    const uint4* wH = W8 + (isB1 ? B_G1H : B_G2H);
    const float* bih = isB1 ? g1_bih : g2_bih;
    const float* bhh = isB1 ? g1_bhh : g2_bhh;
    int* pin = isB1 ? pD : pB1;
    unsigned* oX = (unsigned*)out + (size_t)b*TD*128;   // out1 scratch (mel region, k_post overwrites)
    const unsigned* inP = isB1 ? (gX + 256) : oX;
    const int instr = isB1 ? 384 : 128;
    _Float16* pstB = (_Float16*)(ws + OFF_P) + (size_t)b*TD*512;

    if (tid<256){ hh[tid]=(_Float16)0.f; hf[tid]=0.f; }
    __syncthreads();
    const uint4* h4  = (const uint4*)hh;
    const uint4* dd4 = (const uint4*)dh;

    #pragma unroll 1
    for (int t=0; t<TD; ++t){
      if (tid==0){
        while (__hip_atomic_load(pin+b, __ATOMIC_RELAXED, __HIP_MEMORY_SCOPE_AGENT) < t+1)
          __builtin_amdgcn_s_sleep(1);
      }
      __syncthreads();
      if (tid<128){
        unsigned w = __hip_atomic_load(inP + (size_t)t*instr + tid,
                                       __ATOMIC_RELAXED, __HIP_MEMORY_SCOPE_AGENT);
        ((unsigned*)dh)[tid] = w;
        h2 p = u2h(w);
        df[2*tid]   = (float)p.x;
        df[2*tid+1] = (float)p.y;
      }
      __syncthreads();
      gemv4(wI, wH, dd4, h4, j, ks, scr, tid);
      __syncthreads();
      if (tid<256){
        float s0 = scr[tid*4+0]+scr[(256+tid)*4+0]+scr[(512+tid)*4+0]+scr[(768+tid)*4+0];
        float s1 = scr[tid*4+1]+scr[(256+tid)*4+1]+scr[(512+tid)*4+1]+scr[(768+tid)*4+1];
        float s2 = scr[tid*4+2]+scr[(256+tid)*4+2]+scr[(512+tid)*4+2]+scr[(768+tid)*4+2];
        float s3 = scr[tid*4+3]+scr[(256+tid)*4+3]+scr[(512+tid)*4+3]+scr[(768+tid)*4+3];
        float r = sigmf(s0 + bih[tid]     + bhh[tid]);
        float z = sigmf(s1 + bih[256+tid] + bhh[256+tid]);
        float n = tanhf_(s2 + bih[512+tid] + r*(s3 + bhh[512+tid]));
        float h = (1.f-z)*n + z*hf[tid];
        float dn = h + df[tid];
        hf[tid]=h; hh[tid]=(_Float16)h;
        dh[tid]=(_Float16)dn;                      // reuse dh as output buffer
        if (!isB1) pstB[(size_t)t*512 + tid] = (_Float16)dn;   // p d half
      }
      __syncthreads();
      if (isB1){
        if (tid<128)
          __hip_atomic_store(oX + (size_t)t*128 + tid, ((const unsigned*)dh)[tid],
                             __ATOMIC_RELAXED, __HIP_MEMORY_SCOPE_AGENT);
        __syncthreads();
        if (tid==0)
          __hip_atomic_store(pB1+b, t+1, __ATOMIC_RELEASE, __HIP_MEMORY_SCOPE_AGENT);
      }
    }
  }
}

// ---------------- K5: mel + stop projections ----------------
__global__ void k_post(const float* __restrict__ mel_b, const float* __restrict__ stop_w,
                       const float* __restrict__ stop_b, float* __restrict__ out,
                       char* __restrict__ ws){
  int bt = blockIdx.x;             // b*TD + t
  int b = bt / TD, t = bt % TD;
  int j = threadIdx.x;
  const h2* wm = (const h2*)(ws + OFF_W2) + A_MELW;
  const _Float16* p = (const _Float16*)(ws + OFF_P) + (size_t)bt*512;
  __shared__ _Float16 pl[512];
  ((uint32_t*)pl)[j] = ((const uint32_t*)p)[j];
  __syncthreads();
  const h2* p2 = (const h2*)pl;
  if (j < 160){
    float acc = mel_b[j];
    #pragma unroll 8
    for (int kp=0; kp<256; ++kp) acc = dot2f(wm[kp*160 + j], p2[kp], acc);
    out[(size_t)bt*MR + j] = acc;
  } else if (j == 160){
    float acc = stop_b[0];
    for (int k=0; k<512; ++k) acc += stop_w[k]*(float)pl[k];
    float s = __fdividef(1.f, 1.f + __expf(-acc));
    float* os = out + (size_t)NB*TD*MR + (size_t)NB*TD*TE + (size_t)b*2*TD;
    os[2*t]   = s;
    os[2*t+1] = s;
  }
}

// ---------------- host ----------------
extern "C" void kernel_launch(void* const* d_in, const int* in_sizes, int n_in,
                              void* d_out, int out_size, void* d_ws, size_t ws_size,
                              hipStream_t stream)
{
  const float* enc     = (const float*)d_in[0];
  const float* xin     = (const float*)d_in[1];
  const int*   mlen    = (const int*)  d_in[2];
  const float* pre_w1  = (const float*)d_in[3];
  const float* pre_b1  = (const float*)d_in[4];
  const float* pre_w2  = (const float*)d_in[5];
  const float* pre_b2  = (const float*)d_in[6];
  const float* mem_w   = (const float*)d_in[7];
  const float* att_wih = (const float*)d_in[8];
  const float* att_whh = (const float*)d_in[9];
  const float* att_bih = (const float*)d_in[10];
  const float* att_bhh = (const float*)d_in[11];
  const float* q_w     = (const float*)d_in[12];
  const float* v_w     = (const float*)d_in[13];
  const float* proj_w  = (const float*)d_in[14];
  const float* proj_b  = (const float*)d_in[15];
  const float* g1_wih  = (const float*)d_in[16];
  const float* g1_whh  = (const float*)d_in[17];
  const float* g1_bih  = (const float*)d_in[18];
  const float* g1_bhh  = (const float*)d_in[19];
  const float* g2_wih  = (const float*)d_in[20];
  const float* g2_whh  = (const float*)d_in[21];
  const float* g2_bih  = (const float*)d_in[22];
  const float* g2_bhh  = (const float*)d_in[23];
  const float* mel_w   = (const float*)d_in[24];
  const float* mel_b   = (const float*)d_in[25];
  const float* stop_w  = (const float*)d_in[26];
  const float* stop_b  = (const float*)d_in[27];
  (void)in_sizes; (void)n_in; (void)out_size;

  if (ws_size < WS_NEEDED) return;

  float* out = (float*)d_out;
  char*  ws  = (char*)d_ws;

  auto conv = [&](const float* src, size_t off_h2, int O, int Kh, int k0, int ld){
    int n = O*Kh;
    k_conv<<<(n+255)/256, 256, 0, stream>>>(src, ws, (unsigned)off_h2, O, Kh, k0, ld);
  };
  auto conv8 = [&](const float* src, size_t off16, int O, int Kq, int k0, int ld){
    int n = O*Kq;
    k_conv8<<<(n+255)/256, 256, 0, stream>>>(src, ws, (unsigned)off16, O, Kq, k0, ld);
  };

  // pool A (aux kernels)
  conv(pre_w1,  A_PW1,  256, 80,  0, 160);
  conv(pre_w2,  A_PW2,  128, 128, 0, 256);
  conv(att_wih, A_WIHP, 768, 64,  0, 384);
  conv(mem_w,   A_MEMW, 256, 128, 0, 256);
  conv(mel_w,   A_MELW, 160, 256, 0, 512);
  // pool B (decoder)
  conv8(att_wih, B_ATTC, 768, 32, 128, 384);
  conv8(att_whh, B_ATTH, 768, 32, 0,   256);
  conv8(g1_wih,  B_G1I,  768, 32, 0,   256);
  conv8(g1_whh,  B_G1H,  768, 32, 0,   256);
  conv8(g2_wih,  B_G2I,  768, 32, 0,   256);
  conv8(g2_whh,  B_G2H,  768, 32, 0,   256);
  conv8(proj_w,  B_PROJ, 256, 64, 0,   512);
  conv8(q_w,     B_QW,   256, 32, 0,   256);

  k_pm  <<<NB*TE, 256, 0, stream>>>(enc, ws);
  k_pre <<<NB*TD, 256, 0, stream>>>(xin, pre_b1, pre_b2, att_bih, ws);
  k_zero<<<1, 256, 0, stream>>>(out);
  k_dec <<<4*NB, 1024, 0, stream>>>(mlen, att_bhh, v_w, proj_b,
                                    g1_bih, g1_bhh, g2_bih, g2_bhh, out, ws);
  k_post<<<NB*TD, 256, 0, stream>>>(mel_b, stop_w, stop_b, out, ws);
}

// Round 13
// 4427.869 us; speedup vs baseline: 1.4263x; 1.4263x over previous
//
#include <hip/hip_runtime.h>
#include <math.h>
#include <stdint.h>

// ---------------- problem constants ----------------
#define NB   64
#define TE   256
#define TD   200
#define MR   160

typedef _Float16 h2 __attribute__((ext_vector_type(2)));

__device__ __forceinline__ float dot2f(h2 a, h2 b, float c){
  return __builtin_amdgcn_fdot2(a, b, c, false);
}
__device__ __forceinline__ h2 u2h(unsigned int u){ return __builtin_bit_cast(h2, u); }
__device__ __forceinline__ unsigned int h2u(h2 h){ return __builtin_bit_cast(unsigned int, h); }
__device__ __forceinline__ unsigned f2u(float f){ return __builtin_bit_cast(unsigned, f); }
__device__ __forceinline__ float u2f(unsigned u){ return __builtin_bit_cast(float, u); }

__device__ __forceinline__ float sigmf(float x){
  return __fdividef(1.f, 1.f + __expf(-x));
}
__device__ __forceinline__ float tanhf_(float x){
  float ax = fabsf(x);
  float e  = __expf(-2.f*ax);
  float r  = __fdividef(1.f - e, 1.f + e);
  return copysignf(r, x);
}

// ---------------- workspace layout (bytes) ----------------
static constexpr size_t OFF_PM   = 0;                       // f16 [B][t'][256 d]
static constexpr size_t OFF_ENCH = 8388608;                 // f16 [B][t'][256 d]
static constexpr size_t OFF_GIP  = 16777216;                // f16 [B][TD][768]; gip[t] reused post-consume:
                                                            //   words[0,128)=hA(t) ; [256,384)=d(t)
static constexpr size_t OFF_P    = 36438016;                // f16 [B][TD][512]
static constexpr size_t OFF_W2   = 49545216;                // h2 pool (small mats)
static constexpr size_t OFF_W8   = 50184192;                // uint4 pool (k_dec mats)
static constexpr size_t WS_NEEDED = 52936704;

// pool A (h2 slots): [kp][O] layouts for aux kernels
static constexpr size_t A_PW1  = 0;        // [80 kp][256]
static constexpr size_t A_PW2  = 20480;    // [128 kp][128]
static constexpr size_t A_WIHP = 36864;    // [64 kp][768]
static constexpr size_t A_MEMW = 86016;    // [128 kp][256]
static constexpr size_t A_MELW = 118784;   // [256 kp][160]

// pool B (uint4 slots): [kq][O] with 8 f16 per slot
static constexpr size_t B_ATTC = 0;        // [32 kq][768]
static constexpr size_t B_ATTH = 24576;
static constexpr size_t B_G1I  = 49152;
static constexpr size_t B_G1H  = 73728;
static constexpr size_t B_G2I  = 98304;
static constexpr size_t B_G2H  = 122880;
static constexpr size_t B_PROJ = 147456;   // [64 kq][256]
static constexpr size_t B_QW   = 163840;   // [32 kq][256]

// ---------------- K1a: f32 (O,K) row-major -> f16 [kp][O] (pool A) ----------------
__global__ void k_conv(const float* __restrict__ src, char* __restrict__ ws,
                       unsigned off_h2, int O, int Kh, int k0, int ld){
  int i = blockIdx.x*256 + threadIdx.x;
  if (i >= O*Kh) return;
  int o = i % O, kp = i / O;
  _Float16* dst = (_Float16*)(ws + OFF_W2) + 2*((size_t)off_h2 + i);
  dst[0] = (_Float16)src[(size_t)o*ld + k0 + 2*kp    ];
  dst[1] = (_Float16)src[(size_t)o*ld + k0 + 2*kp + 1];
}

// ---------------- K1b: f32 (O,K) row-major -> f16 [kq][O] packed x8 (pool B) ----------------
__global__ void k_conv8(const float* __restrict__ src, char* __restrict__ ws,
                        unsigned off16, int O, int Kq, int k0, int ld){
  int i = blockIdx.x*256 + threadIdx.x;
  if (i >= O*Kq) return;
  int o = i % O, kq = i / O;
  const float* s = src + (size_t)o*ld + k0 + kq*8;
  h2 p0, p1, p2, p3;
  p0.x=(_Float16)s[0]; p0.y=(_Float16)s[1];
  p1.x=(_Float16)s[2]; p1.y=(_Float16)s[3];
  p2.x=(_Float16)s[4]; p2.y=(_Float16)s[5];
  p3.x=(_Float16)s[6]; p3.y=(_Float16)s[7];
  uint4 r; r.x=h2u(p0); r.y=h2u(p1); r.z=h2u(p2); r.w=h2u(p3);
  ((uint4*)(ws + OFF_W8))[(size_t)off16 + i] = r;
}

// ---------------- K2: processed_memory (pm [b][t'][d]) + enc f16 copy ----------------
__global__ void k_pm(const float* __restrict__ enc, char* __restrict__ ws){
  int bt = blockIdx.x;             // b*256 + t
  int j  = threadIdx.x;
  const h2* mw = (const h2*)(ws + OFF_W2) + A_MEMW;
  _Float16* pmN  = (_Float16*)(ws + OFF_PM);
  _Float16* encH = (_Float16*)(ws + OFF_ENCH);
  __shared__ _Float16 e[256];
  float ev = enc[(size_t)bt*256 + j];
  e[j] = (_Float16)ev;
  encH[(size_t)bt*256 + j] = (_Float16)ev;
  __syncthreads();
  const h2* e2 = (const h2*)e;
  float acc = 0.f;
  #pragma unroll 8
  for (int kp=0; kp<128; ++kp) acc = dot2f(mw[kp*256 + j], e2[kp], acc);
  pmN[(size_t)bt*256 + j] = (_Float16)acc;     // [b][t'][d] layout
}

// ---------------- K3: prenet + gi_pre (all timesteps, parallel) ----------------
__global__ void k_pre(const float* __restrict__ xin, const float* __restrict__ b1,
                      const float* __restrict__ b2, const float* __restrict__ bih,
                      char* __restrict__ ws){
  int bt = blockIdx.x;             // b*TD + t
  int b = bt / TD, t = bt % TD;
  int j = threadIdx.x;
  const h2* w1 = (const h2*)(ws + OFF_W2) + A_PW1;
  const h2* w2 = (const h2*)(ws + OFF_W2) + A_PW2;
  const h2* wp = (const h2*)(ws + OFF_W2) + A_WIHP;
  _Float16* gip = (_Float16*)(ws + OFF_GIP) + (size_t)bt*768;
  __shared__ _Float16 xh[160];
  __shared__ _Float16 a1[256];
  __shared__ _Float16 pr[128];
  if (j < 160)
    xh[j] = (t==0) ? (_Float16)0.f : (_Float16)xin[((size_t)b*TD + (t-1))*MR + j];
  __syncthreads();
  {
    const h2* x2 = (const h2*)xh;
    float acc = b1[j];
    #pragma unroll 8
    for (int kp=0; kp<80; ++kp) acc = dot2f(w1[kp*256 + j], x2[kp], acc);
    a1[j] = (_Float16)fmaxf(acc, 0.f);
  }
  __syncthreads();
  if (j < 128){
    const h2* x2 = (const h2*)a1;
    float acc = b2[j];
    #pragma unroll 8
    for (int kp=0; kp<128; ++kp) acc = dot2f(w2[kp*128 + j], x2[kp], acc);
    pr[j] = (_Float16)fmaxf(acc, 0.f);
  }
  __syncthreads();
  {
    const h2* p2 = (const h2*)pr;
    for (int o=j; o<768; o+=256){
      float acc = bih[o];
      #pragma unroll 8
      for (int kp=0; kp<64; ++kp) acc = dot2f(wp[kp*768 + o], p2[kp], acc);
      gip[o] = (_Float16)acc;
    }
  }
}

// ---------------- K3b: zero per-batch progress flags (stop region of out) ----------------
__global__ void k_zero(float* __restrict__ out){
  int* prog = (int*)(out + (size_t)NB*TD*MR + (size_t)NB*TD*TE);
  if (threadIdx.x < 256) prog[threadIdx.x] = 0;
}

// ---------------- k_dec helpers ----------------
__device__ __forceinline__ float d4dot(uint4 w, uint4 x, float a){
  a = dot2f(u2h(w.x), u2h(x.x), a);
  a = dot2f(u2h(w.y), u2h(x.y), a);
  a = dot2f(u2h(w.z), u2h(x.z), a);
  a = dot2f(u2h(w.w), u2h(x.w), a);
  return a;
}

// dual-operand 4-stream GRU GEMV partials (full K both operands):
// r,z merge I+H partials; n keeps nI,nH separate (n = tanh(nI + r*nH)).
__device__ __forceinline__ void gemv4(const uint4* __restrict__ wI, const uint4* __restrict__ wH,
                                      const uint4* xI, const uint4* xH,
                                      int j, int ks, float* scr, int tid){
  float a0=0.f,a1=0.f,a2=0.f,a3=0.f;
  #pragma unroll 2
  for (int kq=ks*8; kq<ks*8+8; ++kq){
    uint4 xi = xI[kq];
    uint4 xh = xH[kq];
    a0 = d4dot(wI[kq*768 +       j], xi, a0);   // r (I)
    a1 = d4dot(wI[kq*768 + 256 + j], xi, a1);   // z (I)
    a2 = d4dot(wI[kq*768 + 512 + j], xi, a2);   // n (I)
    a0 = d4dot(wH[kq*768 +       j], xh, a0);   // r (+H)
    a1 = d4dot(wH[kq*768 + 256 + j], xh, a1);   // z (+H)
    a3 = d4dot(wH[kq*768 + 512 + j], xh, a3);   // n (H)
  }
  float* r = scr + tid*4;
  r[0]=a0; r[1]=a1; r[2]=a2; r[3]=a3;
}

// ---------------- K4: serial decoder, 4-stage per-batch pipeline ----------------
// grid = 256 blocks x 1024 threads. LDS ~153KB forces exactly ONE block per CU.
// x = (b&7) + 8*(role + 4*(b>>3))  -> batch's 4 roles share an XCD.
// role 0 (A): wAH gemv (393KB, hA local, overlaps P) -> nonlin (+P's wAC
//             partials) -> q (131KB) -> score (pm in swizzled LDS) -> publish
//             UNNORMALIZED e + flag; sum/outA normalize tail overlaps P.
// role 1 (P): on e(t): read e (+in-wave sum); ctx from LDS-resident enc
//             (normalized by 1/sum) -> FULL wAC partials (393KB) -> flag ->
//             proj (262KB) -> d.
// role 2 (B1): GRU1 + residual (786KB).  role 3 (B2): GRU2 + residual -> pst.
// Handoffs: gip[t] words[0,128)=hA (A); [256,384)=d (P).
//   out1(t) -> out mel scratch [0, NB*TD*128) words (B1).
//   uSlot (wAC partials r/z/nI, 768 f32/batch) at word NB*TD*128 + b*768.
//   aSlot (e unnormalized, 256 f32/batch)     at word NB*TD*128 + NB*768 + b*256.
// Single slots race-free: P overwrites uSlot only after reading e(t), which A
// publishes after consuming uSlot in nonlin(t); A overwrites aSlot(t+1) only
// after waiting pP>=t+1 which P sets after reading e(t).
// Flags (out stop-region, k_post overwrites): pP=prog+0, pAl=+64, pD=+128, pB1=+192.
__global__ __launch_bounds__(1024) void k_dec(
    const int*   __restrict__ memlen,
    const float* __restrict__ att_bhh,
    const float* __restrict__ vw,
    const float* __restrict__ proj_b,
    const float* __restrict__ g1_bih, const float* __restrict__ g1_bhh,
    const float* __restrict__ g2_bih, const float* __restrict__ g2_bhh,
    float* __restrict__ out, char* __restrict__ ws)
{
  const int tid  = threadIdx.x;
  const int x    = blockIdx.x;
  const int y    = x >> 3;
  const int role = y & 3;
  const int b    = ((y >> 2) << 3) | (x & 7);
  const int ks   = tid >> 8;       // split-K quarter
  const int j    = tid & 255;      // output index

  const uint4* W8 = (const uint4*)(ws + OFF_W8);
  int* prog = (int*)(out + (size_t)NB*TD*MR + (size_t)NB*TD*TE);
  int* pP   = prog;        // P->A: partials for A's step t ready (value t)
  int* pAl  = prog + 64;   // A->P: e(t)+hA(t) ready (value t+1)
  int* pD   = prog + 128;  // d(t) ready
  int* pB1  = prog + 192;  // out1(t) ready
  unsigned* gX = (unsigned*)((_Float16*)(ws + OFF_GIP) + (size_t)b*TD*768);
  unsigned* uSlot = (unsigned*)out + (size_t)NB*TD*128 + (size_t)b*768;            // wAC partials
  unsigned* aSlot = (unsigned*)out + (size_t)NB*TD*128 + (size_t)NB*768 + (size_t)b*256; // e

  __shared__ __align__(16) _Float16 hAh[256], ctxh[256], hh[256], dh[256];  // 2KB
  __shared__ float hAf[256], hf[256], df[256];                              // 3KB
  __shared__ float qf[256], sc[256], al[256], vl[256];                      // 4KB
  __shared__ float scr[4096];                                               // 16KB
  __shared__ float red2[4];
  __shared__ __align__(16) uint4 pmL[8192];                                 // 128KB: pm (A) / enc (P)

  if (role == 0){
    //================= A: attention recurrence =================
    const uint4* wAH = W8 + B_ATTH;
    const uint4* wQ4 = W8 + B_QW;
    const uint4* pm4 = (const uint4*)(ws + OFF_PM) + (size_t)b*8192;     // [t'][d] uint4
    const _Float16* gipB = (const _Float16*)(ws + OFF_GIP) + (size_t)b*TD*768;
    float* outA = out + (size_t)NB*TD*MR + (size_t)b*TD*TE;
    const int ml = memlen[b];

    // pm -> LDS, XOR-swizzled (granule ^ (row&7)) to break 512B-stride conflicts
    for (int idx = tid; idx < 8192; idx += 1024){
      int tp = idx >> 5, g = idx & 31;
      pmL[(tp<<5) | (g ^ (tp & 7))] = pm4[idx];
    }
    if (tid < 256){ hAh[tid]=(_Float16)0.f; hAf[tid]=0.f; vl[tid]=vw[tid]; }
    __syncthreads();
    const uint4* hA4 = (const uint4*)hAh;

    #pragma unroll 1
    for (int t=0; t<TD; ++t){
      //---- part1: wAH x hA(t-1), hA local (393KB) — overlaps P's partial prod ----
      float a0=0.f, a1=0.f, a3=0.f;
      #pragma unroll 2
      for (int i=0;i<8;++i){
        int kq = ks*8+i;
        uint4 xv = hA4[kq];
        a0 = d4dot(wAH[kq*768 +       j], xv, a0);   // r (H)
        a1 = d4dot(wAH[kq*768 + 256 + j], xv, a1);   // z (H)
        a3 = d4dot(wAH[kq*768 + 512 + j], xv, a3);   // nH
      }
      { float* r = scr + tid*3; r[0]=a0; r[1]=a1; r[2]=a3; }
      if (t > 0 && tid==0){
        while (__hip_atomic_load(pP+b, __ATOMIC_RELAXED, __HIP_MEMORY_SCOPE_AGENT) < t)
          __builtin_amdgcn_s_sleep(1);
      }
      __syncthreads();
      //---- nonlin: merge P's wAC partials, GRU gates ----
      if (tid < 256){
        const _Float16* gp = gipB + (size_t)t*768;
        float s0 = scr[tid*3+0]+scr[(256+tid)*3+0]+scr[(512+tid)*3+0]+scr[(768+tid)*3+0];
        float s1 = scr[tid*3+1]+scr[(256+tid)*3+1]+scr[(512+tid)*3+1]+scr[(768+tid)*3+1];
        float s3 = scr[tid*3+2]+scr[(256+tid)*3+2]+scr[(512+tid)*3+2]+scr[(768+tid)*3+2];
        float s2 = 0.f;
        if (t > 0){
          s0 += u2f(__hip_atomic_load(uSlot +       tid, __ATOMIC_RELAXED, __HIP_MEMORY_SCOPE_AGENT));
          s1 += u2f(__hip_atomic_load(uSlot + 256 + tid, __ATOMIC_RELAXED, __HIP_MEMORY_SCOPE_AGENT));
          s2  = u2f(__hip_atomic_load(uSlot + 512 + tid, __ATOMIC_RELAXED, __HIP_MEMORY_SCOPE_AGENT));
        }
        float r = sigmf(s0 + (float)gp[tid]     + att_bhh[tid]);
        float z = sigmf(s1 + (float)gp[256+tid] + att_bhh[256+tid]);
        float n = tanhf_(s2 + (float)gp[512+tid] + r*(s3 + att_bhh[512+tid]));
        float h = (1.f-z)*n + z*hAf[tid];
        hAf[tid]=h; hAh[tid]=(_Float16)h;
      }
      __syncthreads();
      //---- q = hA @ q_w.T (131KB) ; publish hA(t) alongside ----
      { float a=0.f;
        #pragma unroll 2
        for (int kq=ks*8; kq<ks*8+8; ++kq)
          a = d4dot(wQ4[kq*256 + j], hA4[kq], a);
        scr[tid]=a; }
      if (tid<128)
        __hip_atomic_store(gX + (size_t)t*384 + tid, ((const unsigned*)hAh)[tid],
                           __ATOMIC_RELAXED, __HIP_MEMORY_SCOPE_AGENT);
      __syncthreads();
      if (tid<256) qf[tid] = scr[tid]+scr[256+tid]+scr[512+tid]+scr[768+tid];
      __syncthreads();
      //---- score[t'=j] partials over d (pm from LDS) ----
      { float s=0.f;
        #pragma unroll
        for (int i=0;i<8;++i){
          int g = ks*8 + i;
          uint4 q4 = pmL[(j<<5) | (g ^ (j&7))];
          int d0 = ks*64 + i*8;
          h2 p0=u2h(q4.x), p1=u2h(q4.y), p2=u2h(q4.z), p3=u2h(q4.w);
          s += vl[d0+0]*tanhf_((float)p0.x + qf[d0+0]);
          s += vl[d0+1]*tanhf_((float)p0.y + qf[d0+1]);
          s += vl[d0+2]*tanhf_((float)p1.x + qf[d0+2]);
          s += vl[d0+3]*tanhf_((float)p1.y + qf[d0+3]);
          s += vl[d0+4]*tanhf_((float)p2.x + qf[d0+4]);
          s += vl[d0+5]*tanhf_((float)p2.y + qf[d0+5]);
          s += vl[d0+6]*tanhf_((float)p3.x + qf[d0+6]);
          s += vl[d0+7]*tanhf_((float)p3.y + qf[d0+7]);
        }
        scr[tid]=s; }
      __syncthreads();
      //---- e = exp(score) UNNORMALIZED; publish early (sum moves to P) ----
      if (tid<256){
        float s = scr[tid]+scr[256+tid]+scr[512+tid]+scr[768+tid];
        float e = (tid < ml) ? __expf(s) : 0.f;   // |score|<=sum|v|~10: safe
        sc[tid] = e;
        __hip_atomic_store(aSlot + tid, f2u(e),
                           __ATOMIC_RELAXED, __HIP_MEMORY_SCOPE_AGENT);
      }
      __syncthreads();
      if (tid==0)
        __hip_atomic_store(pAl+b, t+1, __ATOMIC_RELEASE, __HIP_MEMORY_SCOPE_AGENT);
      //---- tail (overlaps P): sum + normalize for attn-score output ----
      if (tid<256){
        float sv = sc[tid];
        #pragma unroll
        for (int o=32;o>0;o>>=1) sv += __shfl_down(sv,o,64);
        if ((tid&63)==0) red2[tid>>6]=sv;
      }
      __syncthreads();
      if (tid<256){
        float sum = red2[0]+red2[1]+red2[2]+red2[3];
        outA[(size_t)t*TE + tid] = sc[tid]*__fdividef(1.f,sum);
      }
    }
  } else if (role == 1){
    //================= P: sum + ctx + full wAC partials + proj =================
    const uint4* wAC  = W8 + B_ATTC;
    const uint4* wPRJ = W8 + B_PROJ;
    const unsigned* encW = (const unsigned*)(ws + OFF_ENCH) + (size_t)b*TE*128;
    _Float16* pstB = (_Float16*)(ws + OFF_P) + (size_t)b*TD*512;
    unsigned* encL = (unsigned*)pmL;                 // 128KB enc in LDS
    const uint4* hA4  = (const uint4*)hAh;
    const uint4* ctx4 = (const uint4*)ctxh;
    const int tsl = tid>>7, dp = tid&127;

    // enc -> LDS (once)
    for (int idx = tid; idx < 32768; idx += 1024) encL[idx] = encW[idx];
    __syncthreads();

    #pragma unroll 1
    for (int t=0; t<TD; ++t){
      //---- wait e(t); read e (+in-wave sum) and hA(t) ----
      if (tid==0){
        while (__hip_atomic_load(pAl+b, __ATOMIC_RELAXED, __HIP_MEMORY_SCOPE_AGENT) < t+1)
          __builtin_amdgcn_s_sleep(1);
      }
      __syncthreads();
      if (tid<256){
        float e = u2f(__hip_atomic_load(aSlot + tid, __ATOMIC_RELAXED, __HIP_MEMORY_SCOPE_AGENT));
        al[tid] = e;
        float sv = e;
        #pragma unroll
        for (int o=32;o>0;o>>=1) sv += __shfl_down(sv,o,64);
        if ((tid&63)==0) red2[tid>>6]=sv;
      }
      if (tid >= 256 && tid < 384)
        ((unsigned*)hAh)[tid-256] = __hip_atomic_load(gX + (size_t)t*384 + (tid-256),
                                                      __ATOMIC_RELAXED, __HIP_MEMORY_SCOPE_AGENT);
      __syncthreads();
      //---- ctx[d] = (sum_t' e[t']*enc[t'][d]) * (1/sum) (enc in LDS) ----
      { float c0=0.f, c1=0.f;
        #pragma unroll 8
        for (int tp=tsl*32; tp<tsl*32+32; ++tp){
          float a = al[tp];
          h2 e = u2h(encL[tp*128 + dp]);
          c0 += a*(float)e.x; c1 += a*(float)e.y;
        }
        scr[tid*2]=c0; scr[tid*2+1]=c1; }
      __syncthreads();
      if (tid<128){
        float c0=0.f, c1=0.f;
        #pragma unroll
        for (int k=0;k<8;++k){ c0 += scr[(k*128+tid)*2]; c1 += scr[(k*128+tid)*2+1]; }
        float rs = __fdividef(1.f, red2[0]+red2[1]+red2[2]+red2[3]);
        h2 c; c.x=(_Float16)(c0*rs); c.y=(_Float16)(c1*rs);
        unsigned w = h2u(c);
        ((unsigned*)ctxh)[tid] = w;
        ((unsigned*)pstB)[(size_t)t*256 + 128 + tid] = w;   // p ctx half
      }
      __syncthreads();
      //---- FULL wAC partials (r/z/nI) for A's step t+1 (393KB, ctx local) ----
      { float a0=0.f, a1=0.f, a2=0.f;
        #pragma unroll 2
        for (int kq=ks*8; kq<ks*8+8; ++kq){
          uint4 xv = ctx4[kq];
          a0 = d4dot(wAC[kq*768 +       j], xv, a0);
          a1 = d4dot(wAC[kq*768 + 256 + j], xv, a1);
          a2 = d4dot(wAC[kq*768 + 512 + j], xv, a2);
        }
        float* r = scr + tid*3; r[0]=a0; r[1]=a1; r[2]=a2; }
      __syncthreads();
      if (tid<256){
        float p0 = scr[tid*3+0]+scr[(256+tid)*3+0]+scr[(512+tid)*3+0]+scr[(768+tid)*3+0];
        float p1 = scr[tid*3+1]+scr[(256+tid)*3+1]+scr[(512+tid)*3+1]+scr[(768+tid)*3+1];
        float p2 = scr[tid*3+2]+scr[(256+tid)*3+2]+scr[(512+tid)*3+2]+scr[(768+tid)*3+2];
        __hip_atomic_store(uSlot +       tid, f2u(p0), __ATOMIC_RELAXED, __HIP_MEMORY_SCOPE_AGENT);
        __hip_atomic_store(uSlot + 256 + tid, f2u(p1), __ATOMIC_RELAXED, __HIP_MEMORY_SCOPE_AGENT);
        __hip_atomic_store(uSlot + 512 + tid, f2u(p2), __ATOMIC_RELAXED, __HIP_MEMORY_SCOPE_AGENT);
      }
      __syncthreads();
      if (tid==0)
        __hip_atomic_store(pP+b, t+1, __ATOMIC_RELEASE, __HIP_MEMORY_SCOPE_AGENT);
      //---- d = [hA, ctx] @ proj_w.T + proj_b (262KB) ----
      { float a=0.f;
        #pragma unroll 2
        for (int kq=ks*16; kq<ks*16+16; ++kq){
          uint4 xa = (kq < 32) ? hA4[kq] : ctx4[kq-32];
          a = d4dot(wPRJ[kq*256 + j], xa, a);
        }
        scr[tid]=a; }
      __syncthreads();
      if (tid<128){
        const int o0 = 2*tid, o1 = o0+1;
        float d0 = scr[o0]+scr[256+o0]+scr[512+o0]+scr[768+o0] + proj_b[o0];
        float d1 = scr[o1]+scr[256+o1]+scr[512+o1]+scr[768+o1] + proj_b[o1];
        h2 p; p.x=(_Float16)d0; p.y=(_Float16)d1;
        __hip_atomic_store(gX + (size_t)t*384 + 256 + tid, h2u(p),
                           __ATOMIC_RELAXED, __HIP_MEMORY_SCOPE_AGENT);
      }
      __syncthreads();
      if (tid==0)
        __hip_atomic_store(pD+b, t+1, __ATOMIC_RELEASE, __HIP_MEMORY_SCOPE_AGENT);
    }
  } else {
    //================= B1 / B2: decoder GRUs =================
    const bool isB1 = (role == 2);
    const uint4* wI = W8 + (isB1 ? B_G1I : B_G2I);
    const uint4* wH = W8 + (isB1 ? B_G1H : B_G2H);
    const float* bih = isB1 ? g1_bih : g2_bih;
    const float* bhh = isB1 ? g1_bhh : g2_bhh;
    int* pin = isB1 ? pD : pB1;
    unsigned* oX = (unsigned*)out + (size_t)b*TD*128;   // out1 scratch (mel region, k_post overwrites)
    const unsigned* inP = isB1 ? (gX + 256) : oX;
    const int instr = isB1 ? 384 : 128;
    _Float16* pstB = (_Float16*)(ws + OFF_P) + (size_t)b*TD*512;

    if (tid<256){ hh[tid]=(_Float16)0.f; hf[tid]=0.f; }
    __syncthreads();
    const uint4* h4  = (const uint4*)hh;
    const uint4* dd4 = (const uint4*)dh;

    #pragma unroll 1
    for (int t=0; t<TD; ++t){
      if (tid==0){
        while (__hip_atomic_load(pin+b, __ATOMIC_RELAXED, __HIP_MEMORY_SCOPE_AGENT) < t+1)
          __builtin_amdgcn_s_sleep(1);
      }
      __syncthreads();
      if (tid<128){
        unsigned w = __hip_atomic_load(inP + (size_t)t*instr + tid,
                                       __ATOMIC_RELAXED, __HIP_MEMORY_SCOPE_AGENT);
        ((unsigned*)dh)[tid] = w;
        h2 p = u2h(w);
        df[2*tid]   = (float)p.x;
        df[2*tid+1] = (float)p.y;
      }
      __syncthreads();
      gemv4(wI, wH, dd4, h4, j, ks, scr, tid);
      __syncthreads();
      if (tid<256){
        float s0 = scr[tid*4+0]+scr[(256+tid)*4+0]+scr[(512+tid)*4+0]+scr[(768+tid)*4+0];
        float s1 = scr[tid*4+1]+scr[(256+tid)*4+1]+scr[(512+tid)*4+1]+scr[(768+tid)*4+1];
        float s2 = scr[tid*4+2]+scr[(256+tid)*4+2]+scr[(512+tid)*4+2]+scr[(768+tid)*4+2];
        float s3 = scr[tid*4+3]+scr[(256+tid)*4+3]+scr[(512+tid)*4+3]+scr[(768+tid)*4+3];
        float r = sigmf(s0 + bih[tid]     + bhh[tid]);
        float z = sigmf(s1 + bih[256+tid] + bhh[256+tid]);
        float n = tanhf_(s2 + bih[512+tid] + r*(s3 + bhh[512+tid]));
        float h = (1.f-z)*n + z*hf[tid];
        float dn = h + df[tid];
        hf[tid]=h; hh[tid]=(_Float16)h;
        dh[tid]=(_Float16)dn;                      // reuse dh as output buffer
        if (!isB1) pstB[(size_t)t*512 + tid] = (_Float16)dn;   // p d half
      }
      __syncthreads();
      if (isB1){
        if (tid<128)
          __hip_atomic_store(oX + (size_t)t*128 + tid, ((const unsigned*)dh)[tid],
                             __ATOMIC_RELAXED, __HIP_MEMORY_SCOPE_AGENT);
        __syncthreads();
        if (tid==0)
          __hip_atomic_store(pB1+b, t+1, __ATOMIC_RELEASE, __HIP_MEMORY_SCOPE_AGENT);
      }
    }
  }
}

// ---------------- K5: mel + stop projections ----------------
__global__ void k_post(const float* __restrict__ mel_b, const float* __restrict__ stop_w,
                       const float* __restrict__ stop_b, float* __restrict__ out,
                       char* __restrict__ ws){
  int bt = blockIdx.x;             // b*TD + t
  int b = bt / TD, t = bt % TD;
  int j = threadIdx.x;
  const h2* wm = (const h2*)(ws + OFF_W2) + A_MELW;
  const _Float16* p = (const _Float16*)(ws + OFF_P) + (size_t)bt*512;
  __shared__ _Float16 pl[512];
  ((uint32_t*)pl)[j] = ((const uint32_t*)p)[j];
  __syncthreads();
  const h2* p2 = (const h2*)pl;
  if (j < 160){
    float acc = mel_b[j];
    #pragma unroll 8
    for (int kp=0; kp<256; ++kp) acc = dot2f(wm[kp*160 + j], p2[kp], acc);
    out[(size_t)bt*MR + j] = acc;
  } else if (j == 160){
    float acc = stop_b[0];
    for (int k=0; k<512; ++k) acc += stop_w[k]*(float)pl[k];
    float s = __fdividef(1.f, 1.f + __expf(-acc));
    float* os = out + (size_t)NB*TD*MR + (size_t)NB*TD*TE + (size_t)b*2*TD;
    os[2*t]   = s;
    os[2*t+1] = s;
  }
}

// ---------------- host ----------------
extern "C" void kernel_launch(void* const* d_in, const int* in_sizes, int n_in,
                              void* d_out, int out_size, void* d_ws, size_t ws_size,
                              hipStream_t stream)
{
  const float* enc     = (const float*)d_in[0];
  const float* xin     = (const float*)d_in[1];
  const int*   mlen    = (const int*)  d_in[2];
  const float* pre_w1  = (const float*)d_in[3];
  const float* pre_b1  = (const float*)d_in[4];
  const float* pre_w2  = (const float*)d_in[5];
  const float* pre_b2  = (const float*)d_in[6];
  const float* mem_w   = (const float*)d_in[7];
  const float* att_wih = (const float*)d_in[8];
  const float* att_whh = (const float*)d_in[9];
  const float* att_bih = (const float*)d_in[10];
  const float* att_bhh = (const float*)d_in[11];
  const float* q_w     = (const float*)d_in[12];
  const float* v_w     = (const float*)d_in[13];
  const float* proj_w  = (const float*)d_in[14];
  const float* proj_b  = (const float*)d_in[15];
  const float* g1_wih  = (const float*)d_in[16];
  const float* g1_whh  = (const float*)d_in[17];
  const float* g1_bih  = (const float*)d_in[18];
  const float* g1_bhh  = (const float*)d_in[19];
  const float* g2_wih  = (const float*)d_in[20];
  const float* g2_whh  = (const float*)d_in[21];
  const float* g2_bih  = (const float*)d_in[22];
  const float* g2_bhh  = (const float*)d_in[23];
  const float* mel_w   = (const float*)d_in[24];
  const float* mel_b   = (const float*)d_in[25];
  const float* stop_w  = (const float*)d_in[26];
  const float* stop_b  = (const float*)d_in[27];
  (void)in_sizes; (void)n_in; (void)out_size;

  if (ws_size < WS_NEEDED) return;

  float* out = (float*)d_out;
  char*  ws  = (char*)d_ws;

  auto conv = [&](const float* src, size_t off_h2, int O, int Kh, int k0, int ld){
    int n = O*Kh;
    k_conv<<<(n+255)/256, 256, 0, stream>>>(src, ws, (unsigned)off_h2, O, Kh, k0, ld);
  };
  auto conv8 = [&](const float* src, size_t off16, int O, int Kq, int k0, int ld){
    int n = O*Kq;
    k_conv8<<<(n+255)/256, 256, 0, stream>>>(src, ws, (unsigned)off16, O, Kq, k0, ld);
  };

  // pool A (aux kernels)
  conv(pre_w1,  A_PW1,  256, 80,  0, 160);
  conv(pre_w2,  A_PW2,  128, 128, 0, 256);
  conv(att_wih, A_WIHP, 768, 64,  0, 384);
  conv(mem_w,   A_MEMW, 256, 128, 0, 256);
  conv(mel_w,   A_MELW, 160, 256, 0, 512);
  // pool B (decoder)
  conv8(att_wih, B_ATTC, 768, 32, 128, 384);
  conv8(att_whh, B_ATTH, 768, 32, 0,   256);
  conv8(g1_wih,  B_G1I,  768, 32, 0,   256);
  conv8(g1_whh,  B_G1H,  768, 32, 0,   256);
  conv8(g2_wih,  B_G2I,  768, 32, 0,   256);
  conv8(g2_whh,  B_G2H,  768, 32, 0,   256);
  conv8(proj_w,  B_PROJ, 256, 64, 0,   512);
  conv8(q_w,     B_QW,   256, 32, 0,   256);

  k_pm  <<<NB*TE, 256, 0, stream>>>(enc, ws);
  k_pre <<<NB*TD, 256, 0, stream>>>(xin, pre_b1, pre_b2, att_bih, ws);
  k_zero<<<1, 256, 0, stream>>>(out);
  k_dec <<<4*NB, 1024, 0, stream>>>(mlen, att_bhh, v_w, proj_b,
                                    g1_bih, g1_bhh, g2_bih, g2_bhh, out, ws);
  k_post<<<NB*TD, 256, 0, stream>>>(mel_b, stop_w, stop_b, out, ws);
}